// Round 1
// baseline (661.007 us; speedup 1.0000x reference)
//
#include <hip/hip_runtime.h>
#include <math.h>

// FFM forward: out[b] = sigmoid( bias + sum_f Wl[g(b,f)]
//                                + sum_{i<j} dot(W[j, g(b,i)], W[i, g(b,j)]) )
// g(b,f) = x[b,f] + f*V_FIELD.
//
// R3: L3-blocked multi-pass. The full pair set touches 380 combos x 1.28 MB
// = 486 MB > 256 MB Infinity Cache, so cross-sample reuse (~1.64x) thrashes.
// Split the 190 pairs into 3 groups (164/161/161 MB footprints) run as
// sequential dispatches over all samples; each pass's footprint is
// L3-resident, cutting HBM fetch toward the ~392 MB compulsory floor.
// Inner gather/FMA structure identical to the verified R2 kernel.

#define FF 20
#define V_FIELD 5000
#define TOTAL (FF * V_FIELD)   // 100000
#define DD 64
#define SPB 4                  // samples per 256-thread block (1 wave each)
#define NP 190                 // F*(F-1)/2 pairs
#define NPP 192                // padded to multiple of 4

template<int PSTART, int PCOUNT, bool FIRST, bool LAST>
__global__ __launch_bounds__(256, 4) void ffm_pass(
    const int* __restrict__ x,
    const float* __restrict__ W,
    const float* __restrict__ Wl,
    const float* __restrict__ bias,
    float* __restrict__ out)
{
    __shared__ int g[SPB][FF];
    __shared__ short pi[NPP], pj[NPP];
    __shared__ unsigned offA[SPB][NPP], offB[SPB][NPP];

    const int t = threadIdx.x;
    const int sbase = blockIdx.x * SPB;

    // Stage vocab indices (global row within a field's 5000-slot range).
    if (t < SPB * FF) {
        const int s = t / FF, f = t % FF;
        g[s][f] = x[(sbase + s) * FF + f] + f * V_FIELD;
    }
    // Pair tables (i<j), same for all samples. Pads -> dummy (0,1).
    if (t < NPP) {
        int pp = (t >= NP) ? 0 : t;
        int i = 0;
        while (pp >= FF - 1 - i) { pp -= FF - 1 - i; ++i; }
        pi[t] = (short)i;
        pj[t] = (short)(i + 1 + pp);
    }
    __syncthreads();

    const int wave = t >> 6;
    const int lane = t & 63;
    const int b = sbase + wave;

    // Per-wave byte-offset tables: offA[p] = &W[j, g_i], offB[p] = &W[i, g_j].
    // Max offset ~512MB fits in u32.
    for (int q = lane; q < 2 * NPP; q += 64) {
        if (q < NPP) {
            const int p = q;
            offA[wave][p] = (unsigned)(pj[p] * TOTAL + g[wave][pi[p]]) * (DD * 4);
        } else {
            const int p = q - NPP;
            offB[wave][p] = (unsigned)(pi[p] * TOTAL + g[wave][pj[p]]) * (DD * 4);
        }
    }
    __syncthreads();

    const int grp = lane >> 4;               // which of 4 pairs this lane serves
    const unsigned chunk = (lane & 15) * 16; // 16B float4 chunk within 256B row
    const char* Wb = (const char*)W;

    float a0 = 0.f, a1 = 0.f, a2 = 0.f, a3 = 0.f;

#pragma unroll 4
    for (int it = 0; it < PCOUNT / 4; ++it) {  // full groups of 4 pairs
        const int p = PSTART + it * 4 + grp;
        const float4 va = *(const float4*)(Wb + (offA[wave][p] + chunk));
        const float4 vb = *(const float4*)(Wb + (offB[wave][p] + chunk));
        a0 = fmaf(va.x, vb.x, a0);
        a1 = fmaf(va.y, vb.y, a1);
        a2 = fmaf(va.z, vb.z, a2);
        a3 = fmaf(va.w, vb.w, a3);
    }
    // Remainder pairs (PCOUNT % 4) on the low lane groups.
    if ((PCOUNT & 3) && grp < (PCOUNT & 3)) {
        const int p = PSTART + (PCOUNT & ~3) + grp;
        const float4 va = *(const float4*)(Wb + (offA[wave][p] + chunk));
        const float4 vb = *(const float4*)(Wb + (offB[wave][p] + chunk));
        a0 = fmaf(va.x, vb.x, a0);
        a1 = fmaf(va.y, vb.y, a1);
        a2 = fmaf(va.z, vb.z, a2);
        a3 = fmaf(va.w, vb.w, a3);
    }
    float acc = (a0 + a1) + (a2 + a3);

    // Linear term once, in the first pass.
    if (FIRST && lane < FF) acc += Wl[g[wave][lane]];

    // Wave-64 reduction.
#pragma unroll
    for (int off = 32; off > 0; off >>= 1)
        acc += __shfl_down(acc, off, 64);

    if (lane == 0) {
        const float r = acc + (FIRST ? bias[0] : out[b]);
        out[b] = LAST ? (1.f / (1.f + expf(-r))) : r;
    }
}

extern "C" void kernel_launch(void* const* d_in, const int* in_sizes, int n_in,
                              void* d_out, int out_size, void* d_ws, size_t ws_size,
                              hipStream_t stream) {
    const int*   x    = (const int*)d_in[0];
    const float* W    = (const float*)d_in[1];
    const float* Wl   = (const float*)d_in[2];
    const float* bias = (const float*)d_in[3];
    float* out = (float*)d_out;

    const int nB = out_size;            // 8192 samples
    dim3 grid(nB / SPB), block(256);

    // 3 L3-sized pair groups: 64 + 63 + 63 = 190 pairs.
    // Footprints 164/161/161 MB < 256 MB Infinity Cache.
    hipLaunchKernelGGL((ffm_pass<0,   64, true,  false>), grid, block, 0, stream,
                       x, W, Wl, bias, out);
    hipLaunchKernelGGL((ffm_pass<64,  63, false, false>), grid, block, 0, stream,
                       x, W, Wl, bias, out);
    hipLaunchKernelGGL((ffm_pass<127, 63, false, true >), grid, block, 0, stream,
                       x, W, Wl, bias, out);
}